// Round 3
// baseline (2393.501 us; speedup 1.0000x reference)
//
#include <hip/hip_runtime.h>
#include <hip/hip_bf16.h>
#include <cstdint>
#include <cstddef>
#include <cmath>

typedef unsigned short u16;
typedef unsigned char  u8;
typedef unsigned int   u32;
typedef __attribute__((ext_vector_type(8))) short short8;   // 8 bf16 MFMA frag
typedef __attribute__((ext_vector_type(4))) float f32x4;    // MFMA accumulator

#define CCH 256
#define HWP 6400   // 80*80

__device__ __forceinline__ u16 f2bf(float f) {
  u32 u = __float_as_uint(f);
  u = (u + 0x7FFFu + ((u >> 16) & 1u)) >> 16;   // RNE
  return (u16)u;
}
__device__ __forceinline__ float bf2f(u16 h) { return __uint_as_float(((u32)h) << 16); }
__device__ __forceinline__ void split3(float v, u16& h, u16& m, u16& l) {
  h = f2bf(v); float r = v - bf2f(h);
  m = f2bf(r); l = f2bf(r - bf2f(m));
}

// ---------------------------------------------------------------------------
// Fold BN into conv weights; emit 3-way split bf16 weights + fp32 biases.
// bnp: [4][3][{g,b,m,v}][C]
// ---------------------------------------------------------------------------
__global__ __launch_bounds__(256) void fold_weights(
    const float* __restrict__ w1, const float* __restrict__ w2,
    const float* __restrict__ bnp,
    u16* __restrict__ w1h, u16* __restrict__ w1m, u16* __restrict__ w1l,
    u16* __restrict__ w2h, u16* __restrict__ w2m, u16* __restrict__ w2l,
    float* __restrict__ b0f, float* __restrict__ b2f)
{
  int i = blockIdx.x >> 8, o = blockIdx.x & 255, c = threadIdx.x;
  const float* bp = bnp + i * 3072;
  double g0 = bp[0 + o],    be0 = bp[256 + o],  m0 = bp[512 + o],  v0 = bp[768 + o];
  double g1 = bp[1024 + o], be1 = bp[1280 + o], m1 = bp[1536 + o], v1 = bp[1792 + o];
  double g2 = bp[2048 + o], be2 = bp[2304 + o], m2 = bp[2560 + o], v2 = bp[2816 + o];
  double s0 = g0 / sqrt(v0 + 1e-5);
  double s1 = g1 / sqrt(v1 + 1e-5);
  double s2 = g2 / sqrt(v2 + 1e-5);
  size_t ro = (size_t)(i * 256 + o) * 256;
  float wa = (float)(s0 * (double)w1[ro + c]);
  float wb = (float)(s1 * s2 * (double)w2[ro + c]);
  u16 h, m, l;
  split3(wa, h, m, l); w1h[ro + c] = h; w1m[ro + c] = m; w1l[ro + c] = l;
  split3(wb, h, m, l); w2h[ro + c] = h; w2m[ro + c] = m; w2l[ro + c] = l;
  if (c == 0) {
    b0f[i * 256 + o] = (float)(be0 - m0 * s0);
    b2f[i * 256 + o] = (float)(s2 * (be1 - m1 * s1) + be2 - m2 * s2);
  }
}

// ---------------------------------------------------------------------------
// Head spike + transpose: x[b][c][p] fp32 -> xs[z][p][c] u8 {0,1} (exact)
// ---------------------------------------------------------------------------
__global__ __launch_bounds__(256) void head_spike(
    const float* __restrict__ x, u8* __restrict__ xs, int b0)
{
  __shared__ u8 tile[64][68];
  int z = blockIdx.z, c0 = blockIdx.y << 6, p0 = blockIdx.x << 6;
  int tid = threadIdx.x;
  const float* xb = x + ((size_t)(b0 + z) * CCH + c0) * HWP + p0;
#pragma unroll
  for (int j = 0; j < 16; ++j) {
    int idx = j * 256 + tid;
    int cl = idx >> 6, pl = idx & 63;
    tile[pl][cl] = (xb[(size_t)cl * HWP + pl] >= 2.0f) ? 1 : 0;
  }
  __syncthreads();
#pragma unroll
  for (int j = 0; j < 4; ++j) {
    int idx = j * 256 + tid;
    int row = idx >> 4, c4 = (idx & 15) << 2;
    *(uchar4*)(xs + ((size_t)z * HWP + p0 + row) * CCH + c0 + c4) =
        *(const uchar4*)&tile[row][c4];
  }
}

// ---------------------------------------------------------------------------
// u8 transpose: in[z][c][p] -> out[b0+z][p][c]   (s after attention)
// ---------------------------------------------------------------------------
__global__ __launch_bounds__(256) void transpose_s(
    const u8* __restrict__ in, u8* __restrict__ out, int b0)
{
  __shared__ u8 tile[64][68];
  int z = blockIdx.z, c0 = blockIdx.y << 6, p0 = blockIdx.x << 6;
  int tid = threadIdx.x;
#pragma unroll
  for (int j = 0; j < 4; ++j) {
    int idx = j * 256 + tid;
    int cl = idx >> 4, p4 = (idx & 15) << 2;
    uchar4 v = *(const uchar4*)(in + ((size_t)z * CCH + c0 + cl) * HWP + p0 + p4);
    tile[p4 + 0][cl] = v.x; tile[p4 + 1][cl] = v.y;
    tile[p4 + 2][cl] = v.z; tile[p4 + 3][cl] = v.w;
  }
  __syncthreads();
#pragma unroll
  for (int j = 0; j < 4; ++j) {
    int idx = j * 256 + tid;
    int row = idx >> 4, c4 = (idx & 15) << 2;
    *(uchar4*)(out + ((size_t)(b0 + z) * HWP + p0 + row) * CCH + c0 + c4) =
        *(const uchar4*)&tile[row][c4];
  }
}

// ---------------------------------------------------------------------------
// GEMM1: T1 = bias + act(binary u8) x W(3-split), 128x128 tile, K=256.
// act [b0in+z][p][c] u8; out T1[z][p][o] fp32 (pixel-major).
// A staged in LDS (padded rows, 16B-aligned); W frags loaded direct from global.
// ---------------------------------------------------------------------------
__global__ __launch_bounds__(256) void gemm1(
    const u8* __restrict__ act, int b0in,
    const u16* __restrict__ WH, const u16* __restrict__ WM, const u16* __restrict__ WL,
    const float* __restrict__ bias, float* __restrict__ T1)
{
  __shared__ alignas(16) u16 As[128 * 40];   // rows padded to 40 u16 (80B, 16B-aligned)
  const int tid = threadIdx.x, wave = tid >> 6, lane = tid & 63;
  const int p0 = blockIdx.x * 128, o0 = blockIdx.y * 128, z = blockIdx.z;
  const int wm = (wave >> 1) * 64, wn = (wave & 1) * 64;
  const int lc = lane & 15, lr = lane >> 4;
  const u8* ab = act + ((size_t)(b0in + z) * HWP + p0) * CCH;

  f32x4 acc[4][4];
#pragma unroll
  for (int i = 0; i < 4; ++i)
#pragma unroll
    for (int j = 0; j < 4; ++j) acc[i][j] = (f32x4){0.f, 0.f, 0.f, 0.f};

  const int srow = tid >> 1, shalf = tid & 1;

  for (int kc = 0; kc < 8; ++kc) {
    __syncthreads();
    uint4 u = *(const uint4*)(ab + (size_t)srow * CCH + kc * 32 + shalf * 16);
    u32 vv[4] = {u.x, u.y, u.z, u.w};
    u32 w[8];
#pragma unroll
    for (int q = 0; q < 4; ++q) {
      u32 v = vv[q];
      w[2 * q]     = ((v & 255u) ? 0x3F80u : 0u) | (((v >> 8) & 255u) ? 0x3F800000u : 0u);
      w[2 * q + 1] = (((v >> 16) & 255u) ? 0x3F80u : 0u) | (((v >> 24) & 255u) ? 0x3F800000u : 0u);
    }
    *(uint4*)&As[srow * 40 + shalf * 16]     = (uint4){w[0], w[1], w[2], w[3]};
    *(uint4*)&As[srow * 40 + shalf * 16 + 8] = (uint4){w[4], w[5], w[6], w[7]};
    __syncthreads();
    short8 af[4];
#pragma unroll
    for (int i = 0; i < 4; ++i)
      af[i] = *(const short8*)&As[(wm + i * 16 + lc) * 40 + lr * 8];
#pragma unroll
    for (int j = 0; j < 4; ++j) {
      size_t wo = (size_t)(o0 + wn + j * 16 + lc) * CCH + kc * 32 + lr * 8;
      short8 bh = *(const short8*)(WH + wo);
      short8 bm = *(const short8*)(WM + wo);
      short8 bl = *(const short8*)(WL + wo);
#pragma unroll
      for (int i = 0; i < 4; ++i) {
        acc[i][j] = __builtin_amdgcn_mfma_f32_16x16x32_bf16(af[i], bl, acc[i][j], 0, 0, 0);
        acc[i][j] = __builtin_amdgcn_mfma_f32_16x16x32_bf16(af[i], bm, acc[i][j], 0, 0, 0);
        acc[i][j] = __builtin_amdgcn_mfma_f32_16x16x32_bf16(af[i], bh, acc[i][j], 0, 0, 0);
      }
    }
  }
  float* tb = T1 + ((size_t)z * HWP + p0) * CCH + o0;
#pragma unroll
  for (int j = 0; j < 4; ++j) {
    int n = wn + j * 16 + lc;
    float bn_ = bias[o0 + n];
#pragma unroll
    for (int i = 0; i < 4; ++i) {
      int m = wm + i * 16 + lr * 4;
#pragma unroll
      for (int r = 0; r < 4; ++r)
        tb[(size_t)(m + r) * CCH + n] = acc[i][j][r] + bn_;
    }
  }
}

// ---------------------------------------------------------------------------
// GEMM2 with FUSED depthwise 3x3: reads T1[z][p][c] fp32, computes dw in fp32
// in-kernel (halo staged in LDS), 3-way splits the result into LDS A-tiles,
// then 6-pass split x split MFMA against W2.
// MODE 0: fp32 channel-major out[(b0+z)][o][p] + bias
// MODE 1: u8 spike (val >= 2) channel-major
// ---------------------------------------------------------------------------
template <int MODE>
__global__ __launch_bounds__(256) void gemm2_dw(
    const float* __restrict__ T1, const float* __restrict__ dwk,
    const u16* __restrict__ WH, const u16* __restrict__ WM, const u16* __restrict__ WL,
    const float* __restrict__ bias, int b0,
    float* __restrict__ outF, u8* __restrict__ outB)
{
  __shared__ alignas(16) float Hs[290 * 16];       // halo, 16 channels
  __shared__ alignas(16) u16 AsH[128 * 40];
  __shared__ alignas(16) u16 AsM[128 * 40];
  __shared__ alignas(16) u16 AsL[128 * 40];
  const int tid = threadIdx.x, wave = tid >> 6, lane = tid & 63;
  const int p0 = blockIdx.x * 128, o0 = blockIdx.y * 128, z = blockIdx.z;
  const int wm = (wave >> 1) * 64, wn = (wave & 1) * 64;
  const int lc = lane & 15, lr = lane >> 4;
  const float* t1b = T1 + (size_t)z * HWP * CCH;

  f32x4 acc[4][4];
#pragma unroll
  for (int i = 0; i < 4; ++i)
#pragma unroll
    for (int j = 0; j < 4; ++j) acc[i][j] = (f32x4){0.f, 0.f, 0.f, 0.f};

  const int dc = tid & 15, slot = tid >> 4;   // dw: channel-in-half, pixel slot

  for (int kc = 0; kc < 8; ++kc) {
#pragma unroll
    for (int h2 = 0; h2 < 2; ++h2) {
      const int chb = kc * 32 + h2 * 16;
      __syncthreads();   // prior Hs/As readers done
#pragma unroll
      for (int t = 0; t < 5; ++t) {
        int i = t * 256 + tid;
        if (i < 1160) {
          int pix = i >> 2, c4 = (i & 3) << 2;
          int P = p0 - 81 + pix;
          float4 v = (P >= 0 && P < HWP)
              ? *(const float4*)(t1b + ((size_t)P * CCH + chb + c4))
              : (float4){0.f, 0.f, 0.f, 0.f};
          *(float4*)&Hs[pix * 16 + c4] = v;
        }
      }
      __syncthreads();
      float wreg[9];
#pragma unroll
      for (int t = 0; t < 9; ++t) wreg[t] = dwk[(chb + dc) * 9 + t];
#pragma unroll
      for (int rep = 0; rep < 8; ++rep) {
        int pl = slot * 8 + rep;
        int p = p0 + pl;
        int y = p / 80, x = p - y * 80;
        float a = 0.f;
#pragma unroll
        for (int dy = -1; dy <= 1; ++dy) {
          int yy = y + dy;
          bool vy = (unsigned)yy < 80u;
#pragma unroll
          for (int dx = -1; dx <= 1; ++dx) {
            int xx = x + dx;
            if (vy && (unsigned)xx < 80u)
              a += wreg[(dy + 1) * 3 + (dx + 1)] * Hs[(pl + 81 + dy * 80 + dx) * 16 + dc];
          }
        }
        u16 hh, mm, ll; split3(a, hh, mm, ll);
        int o = pl * 40 + h2 * 16 + dc;
        AsH[o] = hh; AsM[o] = mm; AsL[o] = ll;
      }
    }
    __syncthreads();   // full 32-k A tile ready
    short8 afH[4], afM[4], afL[4];
#pragma unroll
    for (int i = 0; i < 4; ++i) {
      int o = (wm + i * 16 + lc) * 40 + lr * 8;
      afH[i] = *(const short8*)&AsH[o];
      afM[i] = *(const short8*)&AsM[o];
      afL[i] = *(const short8*)&AsL[o];
    }
#pragma unroll
    for (int j = 0; j < 4; ++j) {
      size_t wo = (size_t)(o0 + wn + j * 16 + lc) * CCH + kc * 32 + lr * 8;
      short8 bh = *(const short8*)(WH + wo);
      short8 bm = *(const short8*)(WM + wo);
      short8 bl = *(const short8*)(WL + wo);
#pragma unroll
      for (int i = 0; i < 4; ++i) {
        acc[i][j] = __builtin_amdgcn_mfma_f32_16x16x32_bf16(afM[i], bm, acc[i][j], 0, 0, 0);
        acc[i][j] = __builtin_amdgcn_mfma_f32_16x16x32_bf16(afL[i], bh, acc[i][j], 0, 0, 0);
        acc[i][j] = __builtin_amdgcn_mfma_f32_16x16x32_bf16(afH[i], bl, acc[i][j], 0, 0, 0);
        acc[i][j] = __builtin_amdgcn_mfma_f32_16x16x32_bf16(afM[i], bh, acc[i][j], 0, 0, 0);
        acc[i][j] = __builtin_amdgcn_mfma_f32_16x16x32_bf16(afH[i], bm, acc[i][j], 0, 0, 0);
        acc[i][j] = __builtin_amdgcn_mfma_f32_16x16x32_bf16(afH[i], bh, acc[i][j], 0, 0, 0);
      }
    }
  }
  // Epilogue: channel-major, m = pixel, n = out-channel.
#pragma unroll
  for (int j = 0; j < 4; ++j) {
    int n = o0 + wn + j * 16 + lc;
    float bn_ = bias[n];
    size_t rowb = ((size_t)(b0 + z) * CCH + n) * HWP + p0;
#pragma unroll
    for (int i = 0; i < 4; ++i) {
      int m = wm + i * 16 + lr * 4;
      if (MODE == 0) {
        float4 o;
        o.x = acc[i][j][0] + bn_; o.y = acc[i][j][1] + bn_;
        o.z = acc[i][j][2] + bn_; o.w = acc[i][j][3] + bn_;
        *(float4*)(outF + rowb + m) = o;
      } else {
        uchar4 o;
        o.x = (acc[i][j][0] + bn_ >= 2.0f) ? 1 : 0;
        o.y = (acc[i][j][1] + bn_ >= 2.0f) ? 1 : 0;
        o.z = (acc[i][j][2] + bn_ >= 2.0f) ? 1 : 0;
        o.w = (acc[i][j][3] + bn_ >= 2.0f) ? 1 : 0;
        *(uchar4*)(outB + rowb + m) = o;
      }
    }
  }
}

// ---------------------------------------------------------------------------
// Attention per (z,c): kv = K^T V (V binary, K 3-split: exact products),
// attn = Q(3-split) kv(3-split) [6 passes], s = (attn >= 8) u8, in-place on V.
// q,k fp32 channel-major. All LDS row strides 96 u16 = 192B (16B-aligned).
// ---------------------------------------------------------------------------
__global__ __launch_bounds__(256) void attn_k(
    const float* __restrict__ qf, const float* __restrict__ kf,
    const u8* __restrict__ vv, u8* __restrict__ s)
{
  __shared__ alignas(16) u16 L[30720];   // 61,440 B
  u32* LW = (u32*)L;
  const int tid = threadIdx.x, wave = tid >> 6, lane = tid & 63;
  const int lc = lane & 15, lr = lane >> 4;
  const size_t off = (size_t)blockIdx.x * HWP;
  u16* KtH = L;          u16* KtM = L + 7680;
  u16* KtL = L + 15360;  u16* Vt  = L + 23040;
#pragma unroll
  for (int t = 0; t < 60; ++t) LW[t * 256 + tid] = 0u;
  __syncthreads();
#pragma unroll
  for (int t = 0; t < 25; ++t) {
    int idx = t * 256 + tid;
    int h = idx / 80, w = idx - h * 80;
    u16 hh, mm, ll; split3(kf[off + idx], hh, mm, ll);
    KtH[w * 96 + h] = hh; KtM[w * 96 + h] = mm; KtL[w * 96 + h] = ll;
    Vt[w * 96 + h] = vv[off + idx] ? (u16)0x3F80 : (u16)0;
  }
  __syncthreads();
  f32x4 kvacc[7];
#pragma unroll
  for (int t = 0; t < 7; ++t) {
    int ti = wave + 4 * t;
    if (ti < 25) {
      int tm = (ti / 5) * 16, tn = (ti % 5) * 16;
      f32x4 a = (f32x4){0.f, 0.f, 0.f, 0.f};
#pragma unroll
      for (int kc = 0; kc < 3; ++kc) {
        int ao = (tm + lc) * 96 + kc * 32 + lr * 8;
        short8 vfr = *(const short8*)&Vt[(tn + lc) * 96 + kc * 32 + lr * 8];
        short8 kl_ = *(const short8*)&KtL[ao];
        short8 km_ = *(const short8*)&KtM[ao];
        short8 kh_ = *(const short8*)&KtH[ao];
        a = __builtin_amdgcn_mfma_f32_16x16x32_bf16(kl_, vfr, a, 0, 0, 0);
        a = __builtin_amdgcn_mfma_f32_16x16x32_bf16(km_, vfr, a, 0, 0, 0);
        a = __builtin_amdgcn_mfma_f32_16x16x32_bf16(kh_, vfr, a, 0, 0, 0);
      }
      kvacc[t] = a;
    }
  }
  __syncthreads();
  // Overlay: Qs (3-split) over Kt; KV tiles over Vt. Zero the k-pads.
  u16* QsH = L;          u16* QsM = L + 7680;  u16* QsL = L + 15360;
  u16* KVH = L + 23040;  u16* KVM = L + 24576; u16* KVL = L + 26112;
#pragma unroll
  for (int t = 0; t < 8; ++t) {
    int i = t * 256 + tid;
    if (i < 1920) {
      int arr = i / 640, rem = i - arr * 640;
      LW[arr * 3840 + (rem >> 3) * 48 + 40 + (rem & 7)] = 0u;
    }
  }
  if (tid < 384) {
    int arr = tid >> 7, rem = tid & 127;
    LW[11520 + arr * 768 + (rem >> 3) * 48 + 40 + (rem & 7)] = 0u;
  }
#pragma unroll
  for (int t = 0; t < 25; ++t) {
    int idx = t * 256 + tid;
    int h = idx / 80, w = idx - h * 80;
    u16 hh, mm, ll; split3(qf[off + idx], hh, mm, ll);
    QsH[h * 96 + w] = hh; QsM[h * 96 + w] = mm; QsL[h * 96 + w] = ll;
  }
  for (int ut = 0; ut < 5; ++ut) {
    __syncthreads();   // Qs/pads visible (it 0); prior KV readers done (it>0)
#pragma unroll
    for (int t = 0; t < 7; ++t) {
      int ti = wave + 4 * t;
      if (ti < 25 && (ti % 5) == ut) {
        int tm = (ti / 5) * 16;
#pragma unroll
        for (int r = 0; r < 4; ++r) {
          u16 hh, mm, ll; split3(kvacc[t][r], hh, mm, ll);
          int o = lc * 96 + tm + lr * 4 + r;
          KVH[o] = hh; KVM[o] = mm; KVL[o] = ll;
        }
      }
    }
    __syncthreads();
    for (int th = wave; th < 5; th += 4) {
      int hm = th * 16;
      f32x4 a = (f32x4){0.f, 0.f, 0.f, 0.f};
#pragma unroll
      for (int kc = 0; kc < 3; ++kc) {
        int qo = (hm + lc) * 96 + kc * 32 + lr * 8;
        int ko = lc * 96 + kc * 32 + lr * 8;
        short8 qh_ = *(const short8*)&QsH[qo];
        short8 qm_ = *(const short8*)&QsM[qo];
        short8 ql_ = *(const short8*)&QsL[qo];
        short8 kh_ = *(const short8*)&KVH[ko];
        short8 km_ = *(const short8*)&KVM[ko];
        short8 kl_ = *(const short8*)&KVL[ko];
        a = __builtin_amdgcn_mfma_f32_16x16x32_bf16(qm_, km_, a, 0, 0, 0);
        a = __builtin_amdgcn_mfma_f32_16x16x32_bf16(ql_, kh_, a, 0, 0, 0);
        a = __builtin_amdgcn_mfma_f32_16x16x32_bf16(qh_, kl_, a, 0, 0, 0);
        a = __builtin_amdgcn_mfma_f32_16x16x32_bf16(qm_, kh_, a, 0, 0, 0);
        a = __builtin_amdgcn_mfma_f32_16x16x32_bf16(qh_, km_, a, 0, 0, 0);
        a = __builtin_amdgcn_mfma_f32_16x16x32_bf16(qh_, kh_, a, 0, 0, 0);
      }
#pragma unroll
      for (int r = 0; r < 4; ++r)
        s[off + (size_t)(hm + lr * 4 + r) * 80 + ut * 16 + lc] = (a[r] >= 8.0f) ? 1 : 0;
    }
  }
}

// ---------------------------------------------------------------------------
extern "C" void kernel_launch(void* const* d_in, const int* in_sizes, int n_in,
                              void* d_out, int out_size, void* d_ws, size_t ws_size,
                              hipStream_t stream)
{
  const float* x   = (const float*)d_in[0];
  const float* w1  = (const float*)d_in[1];
  const float* dwk = (const float*)d_in[2];
  const float* w2  = (const float*)d_in[3];
  const float* bnp = (const float*)d_in[4];
  float* out = (float*)d_out;
  char* ws = (char*)d_ws;

  // Workspace layout (213 MB total)
  u16* W1H = (u16*)(ws + 0);
  u16* W1M = (u16*)(ws + 524288);
  u16* W1L = (u16*)(ws + 1048576);
  u16* W2H = (u16*)(ws + 1572864);
  u16* W2M = (u16*)(ws + 2097152);
  u16* W2L = (u16*)(ws + 2621440);
  float* B0F = (float*)(ws + 3145728);
  float* B2F = (float*)(ws + 3149824);
  u8*    SPM = (u8*)(ws + 3153920);          // s pixel-major, full 16 batches
  u8*    XS  = (u8*)(ws + 29368320);         // xs, half-batch chunk
  float* T1  = (float*)(ws + 42475520);      // fp32 branch tmp, half chunk
  float* QF  = (float*)(ws + 94904320);      // q fp32 CM, half chunk
  float* KF  = (float*)(ws + 147333120);     // k fp32 CM, half chunk
  u8*    V   = (u8*)(ws + 199761920);        // v binary CM (s_cm in-place)

  dim3 gb(256);
  fold_weights<<<dim3(1024), gb, 0, stream>>>(w1, w2, bnp,
      W1H, W1M, W1L, W2H, W2M, W2L, B0F, B2F);

  for (int c = 0; c < 2; ++c) {
    int b0 = c * 8;
    dim3 gh(100, 4, 8), gg(50, 2, 8);
    head_spike<<<gh, gb, 0, stream>>>(x, XS, b0);
    // q branch
    gemm1<<<gg, gb, 0, stream>>>(XS, 0, W1H + 0 * 65536, W1M + 0 * 65536, W1L + 0 * 65536,
                                 B0F + 0, T1);
    gemm2_dw<0><<<gg, gb, 0, stream>>>(T1, dwk + 0 * 2304,
                                       W2H + 0 * 65536, W2M + 0 * 65536, W2L + 0 * 65536,
                                       B2F + 0, 0, QF, nullptr);
    // k branch
    gemm1<<<gg, gb, 0, stream>>>(XS, 0, W1H + 1 * 65536, W1M + 1 * 65536, W1L + 1 * 65536,
                                 B0F + 256, T1);
    gemm2_dw<0><<<gg, gb, 0, stream>>>(T1, dwk + 1 * 2304,
                                       W2H + 1 * 65536, W2M + 1 * 65536, W2L + 1 * 65536,
                                       B2F + 256, 0, KF, nullptr);
    // v branch (binary spike epilogue)
    gemm1<<<gg, gb, 0, stream>>>(XS, 0, W1H + 2 * 65536, W1M + 2 * 65536, W1L + 2 * 65536,
                                 B0F + 512, T1);
    gemm2_dw<1><<<gg, gb, 0, stream>>>(T1, dwk + 2 * 2304,
                                       W2H + 2 * 65536, W2M + 2 * 65536, W2L + 2 * 65536,
                                       B2F + 512, 0, nullptr, V);
    // attention -> s channel-major (in-place over V), then to pixel-major SPM
    attn_k<<<dim3(2048), gb, 0, stream>>>(QF, KF, V, V);
    transpose_s<<<gh, gb, 0, stream>>>(V, SPM, b0);
  }
  // proj branch -> fp32 d_out (channel-major), chunked to fit T1
  for (int c = 0; c < 2; ++c) {
    int b0 = c * 8;
    dim3 gg(50, 2, 8);
    gemm1<<<gg, gb, 0, stream>>>(SPM, b0, W1H + 3 * 65536, W1M + 3 * 65536, W1L + 3 * 65536,
                                 B0F + 768, T1);
    gemm2_dw<0><<<gg, gb, 0, stream>>>(T1, dwk + 3 * 2304,
                                       W2H + 3 * 65536, W2M + 3 * 65536, W2L + 3 * 65536,
                                       B2F + 768, b0, out, nullptr);
  }
}

// Round 5
// 1631.685 us; speedup vs baseline: 1.4669x; 1.4669x over previous
//
#include <hip/hip_runtime.h>
#include <hip/hip_bf16.h>
#include <cstdint>
#include <cstddef>
#include <cmath>

typedef unsigned short u16;
typedef unsigned char  u8;
typedef unsigned int   u32;
typedef __attribute__((ext_vector_type(8))) short short8;   // 8 bf16 MFMA frag
typedef __attribute__((ext_vector_type(4))) float f32x4;    // MFMA accumulator
typedef __attribute__((ext_vector_type(4))) u16 u16x4;

#define CCH 256
#define HWP 6400   // 80*80

__device__ __forceinline__ u16 f2bf(float f) {
  u32 u = __float_as_uint(f);
  u = (u + 0x7FFFu + ((u >> 16) & 1u)) >> 16;   // RNE
  return (u16)u;
}
__device__ __forceinline__ float bf2f(u16 h) { return __uint_as_float(((u32)h) << 16); }
__device__ __forceinline__ void split3(float v, u16& h, u16& m, u16& l) {
  h = f2bf(v); float r = v - bf2f(h);
  m = f2bf(r); l = f2bf(r - bf2f(m));
}
__device__ __forceinline__ void gl_lds16(const void* g, void* l) {
  __builtin_amdgcn_global_load_lds((const __attribute__((address_space(1))) unsigned int*)g,
                                   (__attribute__((address_space(3))) unsigned int*)l,
                                   16, 0, 0);
}

// ---------------------------------------------------------------------------
// Fold BN into conv weights; emit 3-way split bf16 weights + fp32 biases.
// ---------------------------------------------------------------------------
__global__ __launch_bounds__(256) void fold_weights(
    const float* __restrict__ w1, const float* __restrict__ w2,
    const float* __restrict__ bnp,
    u16* __restrict__ w1h, u16* __restrict__ w1m, u16* __restrict__ w1l,
    u16* __restrict__ w2h, u16* __restrict__ w2m, u16* __restrict__ w2l,
    float* __restrict__ b0f, float* __restrict__ b2f)
{
  int i = blockIdx.x >> 8, o = blockIdx.x & 255, c = threadIdx.x;
  const float* bp = bnp + i * 3072;
  double g0 = bp[0 + o],    be0 = bp[256 + o],  m0 = bp[512 + o],  v0 = bp[768 + o];
  double g1 = bp[1024 + o], be1 = bp[1280 + o], m1 = bp[1536 + o], v1 = bp[1792 + o];
  double g2 = bp[2048 + o], be2 = bp[2304 + o], m2 = bp[2560 + o], v2 = bp[2816 + o];
  double s0 = g0 / sqrt(v0 + 1e-5);
  double s1 = g1 / sqrt(v1 + 1e-5);
  double s2 = g2 / sqrt(v2 + 1e-5);
  size_t ro = (size_t)(i * 256 + o) * 256;
  float wa = (float)(s0 * (double)w1[ro + c]);
  float wb = (float)(s1 * s2 * (double)w2[ro + c]);
  u16 h, m, l;
  split3(wa, h, m, l); w1h[ro + c] = h; w1m[ro + c] = m; w1l[ro + c] = l;
  split3(wb, h, m, l); w2h[ro + c] = h; w2m[ro + c] = m; w2l[ro + c] = l;
  if (c == 0) {
    b0f[i * 256 + o] = (float)(be0 - m0 * s0);
    b2f[i * 256 + o] = (float)(s2 * (be1 - m1 * s1) + be2 - m2 * s2);
  }
}

// ---------------------------------------------------------------------------
// Head spike + transpose: x[b][c][p] fp32 -> xs[z][p][c] u8 {0,1} (exact)
// ---------------------------------------------------------------------------
__global__ __launch_bounds__(256) void head_spike(
    const float* __restrict__ x, u8* __restrict__ xs, int b0)
{
  __shared__ u8 tile[64][68];
  int z = blockIdx.z, c0 = blockIdx.y << 6, p0 = blockIdx.x << 6;
  int tid = threadIdx.x;
  const float* xb = x + ((size_t)(b0 + z) * CCH + c0) * HWP + p0;
#pragma unroll
  for (int j = 0; j < 16; ++j) {
    int idx = j * 256 + tid;
    int cl = idx >> 6, pl = idx & 63;
    tile[pl][cl] = (xb[(size_t)cl * HWP + pl] >= 2.0f) ? 1 : 0;
  }
  __syncthreads();
#pragma unroll
  for (int j = 0; j < 4; ++j) {
    int idx = j * 256 + tid;
    int row = idx >> 4, c4 = (idx & 15) << 2;
    *(uchar4*)(xs + ((size_t)z * HWP + p0 + row) * CCH + c0 + c4) =
        *(const uchar4*)&tile[row][c4];
  }
}

// ---------------------------------------------------------------------------
// u8 transpose: in[z][c][p] -> out[b0+z][p][c]   (s after attention)
// ---------------------------------------------------------------------------
__global__ __launch_bounds__(256) void transpose_s(
    const u8* __restrict__ in, u8* __restrict__ out, int b0)
{
  __shared__ u8 tile[64][68];
  int z = blockIdx.z, c0 = blockIdx.y << 6, p0 = blockIdx.x << 6;
  int tid = threadIdx.x;
#pragma unroll
  for (int j = 0; j < 4; ++j) {
    int idx = j * 256 + tid;
    int cl = idx >> 4, p4 = (idx & 15) << 2;
    uchar4 v = *(const uchar4*)(in + ((size_t)z * CCH + c0 + cl) * HWP + p0 + p4);
    tile[p4 + 0][cl] = v.x; tile[p4 + 1][cl] = v.y;
    tile[p4 + 2][cl] = v.z; tile[p4 + 3][cl] = v.w;
  }
  __syncthreads();
#pragma unroll
  for (int j = 0; j < 4; ++j) {
    int idx = j * 256 + tid;
    int row = idx >> 4, c4 = (idx & 15) << 2;
    *(uchar4*)(out + ((size_t)(b0 + z) * HWP + p0 + row) * CCH + c0 + c4) =
        *(const uchar4*)&tile[row][c4];
  }
}

// ---------------------------------------------------------------------------
// GEMM1: T1 = bias + act(binary u8) x W(3-split), 128x128 tile, K=256.
// ---------------------------------------------------------------------------
__global__ __launch_bounds__(256) void gemm1(
    const u8* __restrict__ act, int b0in,
    const u16* __restrict__ WH, const u16* __restrict__ WM, const u16* __restrict__ WL,
    const float* __restrict__ bias, float* __restrict__ T1)
{
  __shared__ alignas(16) u16 As[128 * 40];
  const int tid = threadIdx.x, wave = tid >> 6, lane = tid & 63;
  const int p0 = blockIdx.x * 128, o0 = blockIdx.y * 128, z = blockIdx.z;
  const int wm = (wave >> 1) * 64, wn = (wave & 1) * 64;
  const int lc = lane & 15, lr = lane >> 4;
  const u8* ab = act + ((size_t)(b0in + z) * HWP + p0) * CCH;

  f32x4 acc[4][4];
#pragma unroll
  for (int i = 0; i < 4; ++i)
#pragma unroll
    for (int j = 0; j < 4; ++j) acc[i][j] = (f32x4){0.f, 0.f, 0.f, 0.f};

  const int srow = tid >> 1, shalf = tid & 1;

  for (int kc = 0; kc < 8; ++kc) {
    __syncthreads();
    uint4 u = *(const uint4*)(ab + (size_t)srow * CCH + kc * 32 + shalf * 16);
    u32 vv[4] = {u.x, u.y, u.z, u.w};
    u32 w[8];
#pragma unroll
    for (int q = 0; q < 4; ++q) {
      u32 v = vv[q];
      w[2 * q]     = ((v & 255u) ? 0x3F80u : 0u) | (((v >> 8) & 255u) ? 0x3F800000u : 0u);
      w[2 * q + 1] = (((v >> 16) & 255u) ? 0x3F80u : 0u) | (((v >> 24) & 255u) ? 0x3F800000u : 0u);
    }
    *(uint4*)&As[srow * 40 + shalf * 16]     = (uint4){w[0], w[1], w[2], w[3]};
    *(uint4*)&As[srow * 40 + shalf * 16 + 8] = (uint4){w[4], w[5], w[6], w[7]};
    __syncthreads();
    short8 af[4];
#pragma unroll
    for (int i = 0; i < 4; ++i)
      af[i] = *(const short8*)&As[(wm + i * 16 + lc) * 40 + lr * 8];
#pragma unroll
    for (int j = 0; j < 4; ++j) {
      size_t wo = (size_t)(o0 + wn + j * 16 + lc) * CCH + kc * 32 + lr * 8;
      short8 bh = *(const short8*)(WH + wo);
      short8 bm = *(const short8*)(WM + wo);
      short8 bl = *(const short8*)(WL + wo);
#pragma unroll
      for (int i = 0; i < 4; ++i) {
        acc[i][j] = __builtin_amdgcn_mfma_f32_16x16x32_bf16(af[i], bl, acc[i][j], 0, 0, 0);
        acc[i][j] = __builtin_amdgcn_mfma_f32_16x16x32_bf16(af[i], bm, acc[i][j], 0, 0, 0);
        acc[i][j] = __builtin_amdgcn_mfma_f32_16x16x32_bf16(af[i], bh, acc[i][j], 0, 0, 0);
      }
    }
  }
  float* tb = T1 + ((size_t)z * HWP + p0) * CCH + o0;
#pragma unroll
  for (int j = 0; j < 4; ++j) {
    int n = wn + j * 16 + lc;
    float bn_ = bias[o0 + n];
#pragma unroll
    for (int i = 0; i < 4; ++i) {
      int m = wm + i * 16 + lr * 4;
#pragma unroll
      for (int r = 0; r < 4; ++r)
        tb[(size_t)(m + r) * CCH + n] = acc[i][j][r] + bn_;
    }
  }
}

// ---------------------------------------------------------------------------
// Depthwise 3x3 SAME: T1[z][p][c] fp32 -> 3-way split bf16 planes (pixel-major).
// ---------------------------------------------------------------------------
__global__ __launch_bounds__(256) void dw3(
    const float* __restrict__ t1, const float* __restrict__ dwk,
    u16* __restrict__ oh, u16* __restrict__ om, u16* __restrict__ ol)
{
  __shared__ float wl[2304];   // [c][9]
  int tid = threadIdx.x;
#pragma unroll
  for (int t = 0; t < 9; ++t) wl[t * 256 + tid] = dwk[t * 256 + tid];
  int c4 = (tid & 63) << 2;
  int pl = tid >> 6;
  int p = blockIdx.x * 4 + pl;
  int z = blockIdx.y;
  int y = p / 80, x = p - y * 80;
  __syncthreads();
  float a0 = 0.f, a1 = 0.f, a2 = 0.f, a3 = 0.f;
  const float* base = t1 + (size_t)z * HWP * CCH;
  const float* wc = &wl[c4 * 9];
#pragma unroll
  for (int dy = -1; dy <= 1; ++dy) {
    int yy = y + dy;
    bool vy = (unsigned)yy < 80u;
#pragma unroll
    for (int dx = -1; dx <= 1; ++dx) {
      int xx = x + dx;
      if (vy && (unsigned)xx < 80u) {
        float4 v = *(const float4*)(base + (size_t)(yy * 80 + xx) * CCH + c4);
        int t = (dy + 1) * 3 + (dx + 1);
        a0 += wc[t]      * v.x;
        a1 += wc[9 + t]  * v.y;
        a2 += wc[18 + t] * v.z;
        a3 += wc[27 + t] * v.w;
      }
    }
  }
  u16 h0, m0, l0, h1, m1, l1, h2, m2, l2, h3, m3, l3;
  split3(a0, h0, m0, l0);
  split3(a1, h1, m1, l1);
  split3(a2, h2, m2, l2);
  split3(a3, h3, m3, l3);
  u16x4 vh, vm, vlo;
  vh.x = h0; vh.y = h1; vh.z = h2; vh.w = h3;
  vm.x = m0; vm.y = m1; vm.z = m2; vm.w = m3;
  vlo.x = l0; vlo.y = l1; vlo.z = l2; vlo.w = l3;
  size_t addr = ((size_t)z * HWP + p) * CCH + c4;
  *(u16x4*)(oh + addr) = vh;
  *(u16x4*)(om + addr) = vm;
  *(u16x4*)(ol + addr) = vlo;
}

// ---------------------------------------------------------------------------
// GEMM2: out = bias + dwact(3-split) x W2(3-split), 6 MFMA passes, K=256.
// m97-style: all 6 planes staged via global_load_lds width-16 (48 KB LDS).
// MODE 0: fp32 channel-major out[(b0+z)][o][p] + bias
// MODE 1: u8 spike (val >= 2) channel-major
// ---------------------------------------------------------------------------
template <int MODE>
__global__ __launch_bounds__(256) void gemm2s(
    const u16* __restrict__ AH, const u16* __restrict__ AM, const u16* __restrict__ AL,
    const u16* __restrict__ WH, const u16* __restrict__ WM, const u16* __restrict__ WL,
    const float* __restrict__ bias, int b0,
    float* __restrict__ outF, u8* __restrict__ outB)
{
  __shared__ alignas(16) u16 LAH[4096];
  __shared__ alignas(16) u16 LAM[4096];
  __shared__ alignas(16) u16 LAL[4096];
  __shared__ alignas(16) u16 LWH[4096];
  __shared__ alignas(16) u16 LWM[4096];
  __shared__ alignas(16) u16 LWL[4096];
  const int tid = threadIdx.x, wave = tid >> 6, lane = tid & 63;
  const int p0 = blockIdx.x * 128, o0 = blockIdx.y * 128, z = blockIdx.z;
  const int wm = (wave >> 1) * 64, wn = (wave & 1) * 64;
  const int lc = lane & 15, lr = lane >> 4;
  const char* ahb = (const char*)(AH + ((size_t)z * HWP + p0) * 256);
  const char* amb = (const char*)(AM + ((size_t)z * HWP + p0) * 256);
  const char* alb = (const char*)(AL + ((size_t)z * HWP + p0) * 256);
  const char* whb = (const char*)(WH + (size_t)o0 * 256);
  const char* wmb = (const char*)(WM + (size_t)o0 * 256);
  const char* wlb = (const char*)(WL + (size_t)o0 * 256);

  f32x4 acc[4][4];
#pragma unroll
  for (int i = 0; i < 4; ++i)
#pragma unroll
    for (int j = 0; j < 4; ++j) acc[i][j] = (f32x4){0.f, 0.f, 0.f, 0.f};

  for (int kc = 0; kc < 8; ++kc) {
    const int kof = kc * 64;   // byte offset of 32-element k-slice in 512B row
#pragma unroll
    for (int t = 0; t < 2; ++t) {
      int li = t * 256 + tid;
      int row = li >> 2, ch = li & 3;
      size_t so = (size_t)row * 512 + kof + ch * 16;
      int base = (t * 256 + wave * 64) * 8;   // u16 index, lane0 of wave
      gl_lds16(ahb + so, &LAH[base]);
      gl_lds16(amb + so, &LAM[base]);
      gl_lds16(alb + so, &LAL[base]);
      gl_lds16(whb + so, &LWH[base]);
      gl_lds16(wmb + so, &LWM[base]);
      gl_lds16(wlb + so, &LWL[base]);
    }
    __syncthreads();   // compiler drains vmcnt before barrier
    short8 afH[4], afM[4], afL[4];
#pragma unroll
    for (int i = 0; i < 4; ++i) {
      int o = (wm + i * 16 + lc) * 32 + lr * 8;
      afH[i] = *(const short8*)&LAH[o];
      afM[i] = *(const short8*)&LAM[o];
      afL[i] = *(const short8*)&LAL[o];
    }
#pragma unroll
    for (int j = 0; j < 4; ++j) {
      int o = (wn + j * 16 + lc) * 32 + lr * 8;
      short8 bh = *(const short8*)&LWH[o];
      short8 bm = *(const short8*)&LWM[o];
      short8 bl = *(const short8*)&LWL[o];
#pragma unroll
      for (int i = 0; i < 4; ++i) {
        acc[i][j] = __builtin_amdgcn_mfma_f32_16x16x32_bf16(afM[i], bm, acc[i][j], 0, 0, 0);
        acc[i][j] = __builtin_amdgcn_mfma_f32_16x16x32_bf16(afL[i], bh, acc[i][j], 0, 0, 0);
        acc[i][j] = __builtin_amdgcn_mfma_f32_16x16x32_bf16(afH[i], bl, acc[i][j], 0, 0, 0);
        acc[i][j] = __builtin_amdgcn_mfma_f32_16x16x32_bf16(afM[i], bh, acc[i][j], 0, 0, 0);
        acc[i][j] = __builtin_amdgcn_mfma_f32_16x16x32_bf16(afH[i], bm, acc[i][j], 0, 0, 0);
        acc[i][j] = __builtin_amdgcn_mfma_f32_16x16x32_bf16(afH[i], bh, acc[i][j], 0, 0, 0);
      }
    }
    __syncthreads();
  }
  // Epilogue: channel-major, m = pixel, n = out-channel.
#pragma unroll
  for (int j = 0; j < 4; ++j) {
    int n = o0 + wn + j * 16 + lc;
    float bn_ = bias[n];
    size_t rowb = ((size_t)(b0 + z) * CCH + n) * HWP + p0;
#pragma unroll
    for (int i = 0; i < 4; ++i) {
      int m = wm + i * 16 + lr * 4;
      if (MODE == 0) {
        float4 o;
        o.x = acc[i][j][0] + bn_; o.y = acc[i][j][1] + bn_;
        o.z = acc[i][j][2] + bn_; o.w = acc[i][j][3] + bn_;
        *(float4*)(outF + rowb + m) = o;
      } else {
        uchar4 o;
        o.x = (acc[i][j][0] + bn_ >= 2.0f) ? 1 : 0;
        o.y = (acc[i][j][1] + bn_ >= 2.0f) ? 1 : 0;
        o.z = (acc[i][j][2] + bn_ >= 2.0f) ? 1 : 0;
        o.w = (acc[i][j][3] + bn_ >= 2.0f) ? 1 : 0;
        *(uchar4*)(outB + rowb + m) = o;
      }
    }
  }
}

// ---------------------------------------------------------------------------
// Attention per (z,c): kv = K^T V (V binary, K 3-split), attn = Q kv (6 passes),
// s = (attn >= 8) u8, in-place over V. LDS rows 96 u16 (16B-aligned).
// ---------------------------------------------------------------------------
__global__ __launch_bounds__(256) void attn_k(
    const float* __restrict__ qf, const float* __restrict__ kf,
    const u8* __restrict__ vv, u8* __restrict__ s)
{
  __shared__ alignas(16) u16 L[30720];
  u32* LW = (u32*)L;
  const int tid = threadIdx.x, wave = tid >> 6, lane = tid & 63;
  const int lc = lane & 15, lr = lane >> 4;
  const size_t off = (size_t)blockIdx.x * HWP;
  u16* KtH = L;          u16* KtM = L + 7680;
  u16* KtL = L + 15360;  u16* Vt  = L + 23040;
#pragma unroll
  for (int t = 0; t < 60; ++t) LW[t * 256 + tid] = 0u;
  __syncthreads();
#pragma unroll
  for (int t = 0; t < 25; ++t) {
    int idx = t * 256 + tid;
    int h = idx / 80, w = idx - h * 80;
    u16 hh, mm, ll; split3(kf[off + idx], hh, mm, ll);
    KtH[w * 96 + h] = hh; KtM[w * 96 + h] = mm; KtL[w * 96 + h] = ll;
    Vt[w * 96 + h] = vv[off + idx] ? (u16)0x3F80 : (u16)0;
  }
  __syncthreads();
  f32x4 kvacc[7];
#pragma unroll
  for (int t = 0; t < 7; ++t) {
    int ti = wave + 4 * t;
    if (ti < 25) {
      int tm = (ti / 5) * 16, tn = (ti % 5) * 16;
      f32x4 a = (f32x4){0.f, 0.f, 0.f, 0.f};
#pragma unroll
      for (int kc = 0; kc < 3; ++kc) {
        int ao = (tm + lc) * 96 + kc * 32 + lr * 8;
        short8 vfr = *(const short8*)&Vt[(tn + lc) * 96 + kc * 32 + lr * 8];
        short8 kl_ = *(const short8*)&KtL[ao];
        short8 km_ = *(const short8*)&KtM[ao];
        short8 kh_ = *(const short8*)&KtH[ao];
        a = __builtin_amdgcn_mfma_f32_16x16x32_bf16(kl_, vfr, a, 0, 0, 0);
        a = __builtin_amdgcn_mfma_f32_16x16x32_bf16(km_, vfr, a, 0, 0, 0);
        a = __builtin_amdgcn_mfma_f32_16x16x32_bf16(kh_, vfr, a, 0, 0, 0);
      }
      kvacc[t] = a;
    }
  }
  __syncthreads();
  u16* QsH = L;          u16* QsM = L + 7680;  u16* QsL = L + 15360;
  u16* KVH = L + 23040;  u16* KVM = L + 24576; u16* KVL = L + 26112;
#pragma unroll
  for (int t = 0; t < 8; ++t) {
    int i = t * 256 + tid;
    if (i < 1920) {
      int arr = i / 640, rem = i - arr * 640;
      LW[arr * 3840 + (rem >> 3) * 48 + 40 + (rem & 7)] = 0u;
    }
  }
  if (tid < 384) {
    int arr = tid >> 7, rem = tid & 127;
    LW[11520 + arr * 768 + (rem >> 3) * 48 + 40 + (rem & 7)] = 0u;
  }
#pragma unroll
  for (int t = 0; t < 25; ++t) {
    int idx = t * 256 + tid;
    int h = idx / 80, w = idx - h * 80;
    u16 hh, mm, ll; split3(qf[off + idx], hh, mm, ll);
    QsH[h * 96 + w] = hh; QsM[h * 96 + w] = mm; QsL[h * 96 + w] = ll;
  }
  for (int ut = 0; ut < 5; ++ut) {
    __syncthreads();
#pragma unroll
    for (int t = 0; t < 7; ++t) {
      int ti = wave + 4 * t;
      if (ti < 25 && (ti % 5) == ut) {
        int tm = (ti / 5) * 16;
#pragma unroll
        for (int r = 0; r < 4; ++r) {
          u16 hh, mm, ll; split3(kvacc[t][r], hh, mm, ll);
          int o = lc * 96 + tm + lr * 4 + r;
          KVH[o] = hh; KVM[o] = mm; KVL[o] = ll;
        }
      }
    }
    __syncthreads();
    for (int th = wave; th < 5; th += 4) {
      int hm = th * 16;
      f32x4 a = (f32x4){0.f, 0.f, 0.f, 0.f};
#pragma unroll
      for (int kc = 0; kc < 3; ++kc) {
        int qo = (hm + lc) * 96 + kc * 32 + lr * 8;
        int ko = lc * 96 + kc * 32 + lr * 8;
        short8 qh_ = *(const short8*)&QsH[qo];
        short8 qm_ = *(const short8*)&QsM[qo];
        short8 ql_ = *(const short8*)&QsL[qo];
        short8 kh_ = *(const short8*)&KVH[ko];
        short8 km_ = *(const short8*)&KVM[ko];
        short8 kl_ = *(const short8*)&KVL[ko];
        a = __builtin_amdgcn_mfma_f32_16x16x32_bf16(qm_, km_, a, 0, 0, 0);
        a = __builtin_amdgcn_mfma_f32_16x16x32_bf16(ql_, kh_, a, 0, 0, 0);
        a = __builtin_amdgcn_mfma_f32_16x16x32_bf16(qh_, kl_, a, 0, 0, 0);
        a = __builtin_amdgcn_mfma_f32_16x16x32_bf16(qm_, kh_, a, 0, 0, 0);
        a = __builtin_amdgcn_mfma_f32_16x16x32_bf16(qh_, km_, a, 0, 0, 0);
        a = __builtin_amdgcn_mfma_f32_16x16x32_bf16(qh_, kh_, a, 0, 0, 0);
      }
#pragma unroll
      for (int r = 0; r < 4; ++r)
        s[off + (size_t)(hm + lr * 4 + r) * 80 + ut * 16 + lc] = (a[r] >= 8.0f) ? 1 : 0;
    }
  }
}

// ---------------------------------------------------------------------------
extern "C" void kernel_launch(void* const* d_in, const int* in_sizes, int n_in,
                              void* d_out, int out_size, void* d_ws, size_t ws_size,
                              hipStream_t stream)
{
  const float* x   = (const float*)d_in[0];
  const float* w1  = (const float*)d_in[1];
  const float* dwk = (const float*)d_in[2];
  const float* w2  = (const float*)d_in[3];
  const float* bnp = (const float*)d_in[4];
  float* out = (float*)d_out;
  char* ws = (char*)d_ws;

  // Workspace layout (~292 MB total)
  u16* W1H = (u16*)(ws + 0);
  u16* W1M = (u16*)(ws + 524288);
  u16* W1L = (u16*)(ws + 1048576);
  u16* W2H = (u16*)(ws + 1572864);
  u16* W2M = (u16*)(ws + 2097152);
  u16* W2L = (u16*)(ws + 2621440);
  float* B0F = (float*)(ws + 3145728);
  float* B2F = (float*)(ws + 3149824);
  u8*    SPM = (u8*)(ws + 3153920);          // s pixel-major, full 16 batches
  u8*    XS  = (u8*)(ws + 29368320);         // xs, half-batch chunk
  float* T1  = (float*)(ws + 42475520);      // fp32 branch tmp, half chunk
  float* QF  = (float*)(ws + 94904320);      // q fp32 CM, half chunk
  float* KF  = (float*)(ws + 147333120);     // k fp32 CM, half chunk
  u8*    V   = (u8*)(ws + 199761920);        // v binary CM (s_cm in-place)
  u16*   D2H = (u16*)(ws + 212869120);       // dw split hi, pixel-major
  u16*   D2M = (u16*)(ws + 239083520);
  u16*   D2L = (u16*)(ws + 265297920);       // ends 291512320

  dim3 gb(256);
  fold_weights<<<dim3(1024), gb, 0, stream>>>(w1, w2, bnp,
      W1H, W1M, W1L, W2H, W2M, W2L, B0F, B2F);

  for (int c = 0; c < 2; ++c) {
    int b0 = c * 8;
    dim3 gh(100, 4, 8), gg(50, 2, 8), gd(1600, 8);
    head_spike<<<gh, gb, 0, stream>>>(x, XS, b0);
    // q branch
    gemm1<<<gg, gb, 0, stream>>>(XS, 0, W1H + 0 * 65536, W1M + 0 * 65536, W1L + 0 * 65536,
                                 B0F + 0, T1);
    dw3<<<gd, gb, 0, stream>>>(T1, dwk + 0 * 2304, D2H, D2M, D2L);
    gemm2s<0><<<gg, gb, 0, stream>>>(D2H, D2M, D2L,
                                     W2H + 0 * 65536, W2M + 0 * 65536, W2L + 0 * 65536,
                                     B2F + 0, 0, QF, nullptr);
    // k branch
    gemm1<<<gg, gb, 0, stream>>>(XS, 0, W1H + 1 * 65536, W1M + 1 * 65536, W1L + 1 * 65536,
                                 B0F + 256, T1);
    dw3<<<gd, gb, 0, stream>>>(T1, dwk + 1 * 2304, D2H, D2M, D2L);
    gemm2s<0><<<gg, gb, 0, stream>>>(D2H, D2M, D2L,
                                     W2H + 1 * 65536, W2M + 1 * 65536, W2L + 1 * 65536,
                                     B2F + 256, 0, KF, nullptr);
    // v branch (binary spike epilogue)
    gemm1<<<gg, gb, 0, stream>>>(XS, 0, W1H + 2 * 65536, W1M + 2 * 65536, W1L + 2 * 65536,
                                 B0F + 512, T1);
    dw3<<<gd, gb, 0, stream>>>(T1, dwk + 2 * 2304, D2H, D2M, D2L);
    gemm2s<1><<<gg, gb, 0, stream>>>(D2H, D2M, D2L,
                                     W2H + 2 * 65536, W2M + 2 * 65536, W2L + 2 * 65536,
                                     B2F + 512, 0, nullptr, V);
    // attention -> s channel-major (in-place over V), then to pixel-major SPM
    attn_k<<<dim3(2048), gb, 0, stream>>>(QF, KF, V, V);
    transpose_s<<<gh, gb, 0, stream>>>(V, SPM, b0);
  }
  // proj branch -> fp32 d_out (channel-major), chunked to fit T1
  for (int c = 0; c < 2; ++c) {
    int b0 = c * 8;
    dim3 gg(50, 2, 8), gd(1600, 8);
    gemm1<<<gg, gb, 0, stream>>>(SPM, b0, W1H + 3 * 65536, W1M + 3 * 65536, W1L + 3 * 65536,
                                 B0F + 768, T1);
    dw3<<<gd, gb, 0, stream>>>(T1, dwk + 3 * 2304, D2H, D2M, D2L);
    gemm2s<0><<<gg, gb, 0, stream>>>(D2H, D2M, D2L,
                                     W2H + 3 * 65536, W2M + 3 * 65536, W2L + 3 * 65536,
                                     B2F + 768, b0, out, nullptr);
  }
}

// Round 6
// 1398.175 us; speedup vs baseline: 1.7119x; 1.1670x over previous
//
#include <hip/hip_runtime.h>
#include <hip/hip_bf16.h>
#include <cstdint>
#include <cstddef>
#include <cmath>

typedef unsigned short u16;
typedef unsigned char  u8;
typedef unsigned int   u32;
typedef __attribute__((ext_vector_type(8))) short short8;   // 8 bf16 MFMA frag
typedef __attribute__((ext_vector_type(4))) float f32x4;    // MFMA accumulator
typedef __attribute__((ext_vector_type(4))) u16 u16x4;

#define CCH 256
#define HWP 6400   // 80*80

__device__ __forceinline__ u16 f2bf(float f) {
  u32 u = __float_as_uint(f);
  u = (u + 0x7FFFu + ((u >> 16) & 1u)) >> 16;   // RNE
  return (u16)u;
}
__device__ __forceinline__ float bf2f(u16 h) { return __uint_as_float(((u32)h) << 16); }
__device__ __forceinline__ void split3(float v, u16& h, u16& m, u16& l) {
  h = f2bf(v); float r = v - bf2f(h);
  m = f2bf(r); l = f2bf(r - bf2f(m));
}
__device__ __forceinline__ void gl_lds16(const void* g, void* l) {
  __builtin_amdgcn_global_load_lds((const __attribute__((address_space(1))) unsigned int*)g,
                                   (__attribute__((address_space(3))) unsigned int*)l,
                                   16, 0, 0);
}

// ---------------------------------------------------------------------------
// Fold BN into conv weights; emit 3-way split bf16 weights + fp32 biases.
// ---------------------------------------------------------------------------
__global__ __launch_bounds__(256) void fold_weights(
    const float* __restrict__ w1, const float* __restrict__ w2,
    const float* __restrict__ bnp,
    u16* __restrict__ w1h, u16* __restrict__ w1m, u16* __restrict__ w1l,
    u16* __restrict__ w2h, u16* __restrict__ w2m, u16* __restrict__ w2l,
    float* __restrict__ b0f, float* __restrict__ b2f)
{
  int i = blockIdx.x >> 8, o = blockIdx.x & 255, c = threadIdx.x;
  const float* bp = bnp + i * 3072;
  double g0 = bp[0 + o],    be0 = bp[256 + o],  m0 = bp[512 + o],  v0 = bp[768 + o];
  double g1 = bp[1024 + o], be1 = bp[1280 + o], m1 = bp[1536 + o], v1 = bp[1792 + o];
  double g2 = bp[2048 + o], be2 = bp[2304 + o], m2 = bp[2560 + o], v2 = bp[2816 + o];
  double s0 = g0 / sqrt(v0 + 1e-5);
  double s1 = g1 / sqrt(v1 + 1e-5);
  double s2 = g2 / sqrt(v2 + 1e-5);
  size_t ro = (size_t)(i * 256 + o) * 256;
  float wa = (float)(s0 * (double)w1[ro + c]);
  float wb = (float)(s1 * s2 * (double)w2[ro + c]);
  u16 h, m, l;
  split3(wa, h, m, l); w1h[ro + c] = h; w1m[ro + c] = m; w1l[ro + c] = l;
  split3(wb, h, m, l); w2h[ro + c] = h; w2m[ro + c] = m; w2l[ro + c] = l;
  if (c == 0) {
    b0f[i * 256 + o] = (float)(be0 - m0 * s0);
    b2f[i * 256 + o] = (float)(s2 * (be1 - m1 * s1) + be2 - m2 * s2);
  }
}

// ---------------------------------------------------------------------------
// Head spike + transpose: x[b][c][p] fp32 -> xs[z][p][c] u8 {0,1} (exact)
// ---------------------------------------------------------------------------
__global__ __launch_bounds__(256) void head_spike(
    const float* __restrict__ x, u8* __restrict__ xs, int b0)
{
  __shared__ u8 tile[64][68];
  int z = blockIdx.z, c0 = blockIdx.y << 6, p0 = blockIdx.x << 6;
  int tid = threadIdx.x;
  const float* xb = x + ((size_t)(b0 + z) * CCH + c0) * HWP + p0;
#pragma unroll
  for (int j = 0; j < 16; ++j) {
    int idx = j * 256 + tid;
    int cl = idx >> 6, pl = idx & 63;
    tile[pl][cl] = (xb[(size_t)cl * HWP + pl] >= 2.0f) ? 1 : 0;
  }
  __syncthreads();
#pragma unroll
  for (int j = 0; j < 4; ++j) {
    int idx = j * 256 + tid;
    int row = idx >> 4, c4 = (idx & 15) << 2;
    *(uchar4*)(xs + ((size_t)z * HWP + p0 + row) * CCH + c0 + c4) =
        *(const uchar4*)&tile[row][c4];
  }
}

// ---------------------------------------------------------------------------
// u8 transpose: in[z][c][p] -> out[b0+z][p][c]   (s after attention)
// ---------------------------------------------------------------------------
__global__ __launch_bounds__(256) void transpose_s(
    const u8* __restrict__ in, u8* __restrict__ out, int b0)
{
  __shared__ u8 tile[64][68];
  int z = blockIdx.z, c0 = blockIdx.y << 6, p0 = blockIdx.x << 6;
  int tid = threadIdx.x;
#pragma unroll
  for (int j = 0; j < 4; ++j) {
    int idx = j * 256 + tid;
    int cl = idx >> 4, p4 = (idx & 15) << 2;
    uchar4 v = *(const uchar4*)(in + ((size_t)z * CCH + c0 + cl) * HWP + p0 + p4);
    tile[p4 + 0][cl] = v.x; tile[p4 + 1][cl] = v.y;
    tile[p4 + 2][cl] = v.z; tile[p4 + 3][cl] = v.w;
  }
  __syncthreads();
#pragma unroll
  for (int j = 0; j < 4; ++j) {
    int idx = j * 256 + tid;
    int row = idx >> 4, c4 = (idx & 15) << 2;
    *(uchar4*)(out + ((size_t)(b0 + z) * HWP + p0 + row) * CCH + c0 + c4) =
        *(const uchar4*)&tile[row][c4];
  }
}

// ---------------------------------------------------------------------------
// GEMM1: T1 = bias + act(binary u8) x W(3-split), 128x128 tile, K=256.
// W staged via swizzled global_load_lds (2-way frag reads).
// ---------------------------------------------------------------------------
__global__ __launch_bounds__(256) void gemm1(
    const u8* __restrict__ act, int b0in,
    const u16* __restrict__ WH, const u16* __restrict__ WM, const u16* __restrict__ WL,
    const float* __restrict__ bias, float* __restrict__ T1)
{
  __shared__ alignas(16) u16 As[128 * 40];
  __shared__ alignas(16) u16 LWH[4096];
  __shared__ alignas(16) u16 LWM[4096];
  __shared__ alignas(16) u16 LWL[4096];
  const int tid = threadIdx.x, wave = tid >> 6, lane = tid & 63;
  const int p0 = blockIdx.x * 128, o0 = blockIdx.y * 128, z = blockIdx.z;
  const int wm = (wave >> 1) * 64, wn = (wave & 1) * 64;
  const int lc = lane & 15, lr = lane >> 4;
  const u8* ab = act + ((size_t)(b0in + z) * HWP + p0) * CCH;
  const char* whb = (const char*)(WH + (size_t)o0 * 256);
  const char* wmb = (const char*)(WM + (size_t)o0 * 256);
  const char* wlb = (const char*)(WL + (size_t)o0 * 256);

  f32x4 acc[4][4];
#pragma unroll
  for (int i = 0; i < 4; ++i)
#pragma unroll
    for (int j = 0; j < 4; ++j) acc[i][j] = (f32x4){0.f, 0.f, 0.f, 0.f};

  const int srow = tid >> 1, shalf = tid & 1;

  for (int kc = 0; kc < 8; ++kc) {
    const int kof = kc * 64;
    __syncthreads();
    // kick W DMA (swizzled granules; same 64B line per 4 lanes)
#pragma unroll
    for (int t = 0; t < 2; ++t) {
      int li = t * 256 + tid;
      int row = li >> 2, ch = li & 3;
      int chp = (ch - row - (row >> 2)) & 3;
      size_t so = (size_t)row * 512 + kof + chp * 16;
      int base = (t * 256 + wave * 64) * 8;
      gl_lds16(whb + so, &LWH[base]);
      gl_lds16(wmb + so, &LWM[base]);
      gl_lds16(wlb + so, &LWL[base]);
    }
    // expand binary act into As (overlaps the DMA)
    uint4 u = *(const uint4*)(ab + (size_t)srow * CCH + kc * 32 + shalf * 16);
    u32 vv[4] = {u.x, u.y, u.z, u.w};
    u32 w[8];
#pragma unroll
    for (int q = 0; q < 4; ++q) {
      u32 v = vv[q];
      w[2 * q]     = ((v & 255u) ? 0x3F80u : 0u) | (((v >> 8) & 255u) ? 0x3F800000u : 0u);
      w[2 * q + 1] = (((v >> 16) & 255u) ? 0x3F80u : 0u) | (((v >> 24) & 255u) ? 0x3F800000u : 0u);
    }
    *(uint4*)&As[srow * 40 + shalf * 16]     = (uint4){w[0], w[1], w[2], w[3]};
    *(uint4*)&As[srow * 40 + shalf * 16 + 8] = (uint4){w[4], w[5], w[6], w[7]};
    __syncthreads();
    short8 af[4];
#pragma unroll
    for (int i = 0; i < 4; ++i)
      af[i] = *(const short8*)&As[(wm + i * 16 + lc) * 40 + lr * 8];
#pragma unroll
    for (int j = 0; j < 4; ++j) {
      int row = wn + j * 16 + lc;
      int o = row * 32 + ((lr + lc + (lc >> 2)) & 3) * 8;
      short8 bh = *(const short8*)&LWH[o];
      short8 bm = *(const short8*)&LWM[o];
      short8 bl = *(const short8*)&LWL[o];
#pragma unroll
      for (int i = 0; i < 4; ++i) {
        acc[i][j] = __builtin_amdgcn_mfma_f32_16x16x32_bf16(af[i], bl, acc[i][j], 0, 0, 0);
        acc[i][j] = __builtin_amdgcn_mfma_f32_16x16x32_bf16(af[i], bm, acc[i][j], 0, 0, 0);
        acc[i][j] = __builtin_amdgcn_mfma_f32_16x16x32_bf16(af[i], bh, acc[i][j], 0, 0, 0);
      }
    }
  }
  float* tb = T1 + ((size_t)z * HWP + p0) * CCH + o0;
#pragma unroll
  for (int j = 0; j < 4; ++j) {
    int n = wn + j * 16 + lc;
    float bn_ = bias[o0 + n];
#pragma unroll
    for (int i = 0; i < 4; ++i) {
      int m = wm + i * 16 + lr * 4;
#pragma unroll
      for (int r = 0; r < 4; ++r)
        tb[(size_t)(m + r) * CCH + n] = acc[i][j][r] + bn_;
    }
  }
}

// ---------------------------------------------------------------------------
// Depthwise 3x3 SAME: T1[z][p][c] fp32 -> 3-way split bf16 planes (pixel-major).
// ---------------------------------------------------------------------------
__global__ __launch_bounds__(256) void dw3(
    const float* __restrict__ t1, const float* __restrict__ dwk,
    u16* __restrict__ oh, u16* __restrict__ om, u16* __restrict__ ol)
{
  __shared__ float wl[2304];   // [c][9]
  int tid = threadIdx.x;
#pragma unroll
  for (int t = 0; t < 9; ++t) wl[t * 256 + tid] = dwk[t * 256 + tid];
  int c4 = (tid & 63) << 2;
  int pl = tid >> 6;
  int p = blockIdx.x * 4 + pl;
  int z = blockIdx.y;
  int y = p / 80, x = p - y * 80;
  __syncthreads();
  float a0 = 0.f, a1 = 0.f, a2 = 0.f, a3 = 0.f;
  const float* base = t1 + (size_t)z * HWP * CCH;
  const float* wc = &wl[c4 * 9];
#pragma unroll
  for (int dy = -1; dy <= 1; ++dy) {
    int yy = y + dy;
    bool vy = (unsigned)yy < 80u;
#pragma unroll
    for (int dx = -1; dx <= 1; ++dx) {
      int xx = x + dx;
      if (vy && (unsigned)xx < 80u) {
        float4 v = *(const float4*)(base + (size_t)(yy * 80 + xx) * CCH + c4);
        int t = (dy + 1) * 3 + (dx + 1);
        a0 += wc[t]      * v.x;
        a1 += wc[9 + t]  * v.y;
        a2 += wc[18 + t] * v.z;
        a3 += wc[27 + t] * v.w;
      }
    }
  }
  u16 h0, m0, l0, h1, m1, l1, h2, m2, l2, h3, m3, l3;
  split3(a0, h0, m0, l0);
  split3(a1, h1, m1, l1);
  split3(a2, h2, m2, l2);
  split3(a3, h3, m3, l3);
  u16x4 vh, vm, vlo;
  vh.x = h0; vh.y = h1; vh.z = h2; vh.w = h3;
  vm.x = m0; vm.y = m1; vm.z = m2; vm.w = m3;
  vlo.x = l0; vlo.y = l1; vlo.z = l2; vlo.w = l3;
  size_t addr = ((size_t)z * HWP + p) * CCH + c4;
  *(u16x4*)(oh + addr) = vh;
  *(u16x4*)(om + addr) = vm;
  *(u16x4*)(ol + addr) = vlo;
}

// ---------------------------------------------------------------------------
// GEMM2: out = bias + dwact(3-split) x W2(3-split), 6 MFMA passes, K=256.
// Swizzled global_load_lds staging (granule rotation -> 2-way frag reads).
// MODE 0: fp32 channel-major out[(b0+z)][o][p] + bias
// MODE 1: u8 spike (val >= 2) channel-major
// ---------------------------------------------------------------------------
template <int MODE>
__global__ __launch_bounds__(256) void gemm2s(
    const u16* __restrict__ AH, const u16* __restrict__ AM, const u16* __restrict__ AL,
    const u16* __restrict__ WH, const u16* __restrict__ WM, const u16* __restrict__ WL,
    const float* __restrict__ bias, int b0,
    float* __restrict__ outF, u8* __restrict__ outB)
{
  __shared__ alignas(16) u16 LAH[4096];
  __shared__ alignas(16) u16 LAM[4096];
  __shared__ alignas(16) u16 LAL[4096];
  __shared__ alignas(16) u16 LWH[4096];
  __shared__ alignas(16) u16 LWM[4096];
  __shared__ alignas(16) u16 LWL[4096];
  const int tid = threadIdx.x, wave = tid >> 6, lane = tid & 63;
  const int p0 = blockIdx.x * 128, o0 = blockIdx.y * 128, z = blockIdx.z;
  const int wm = (wave >> 1) * 64, wn = (wave & 1) * 64;
  const int lc = lane & 15, lr = lane >> 4;
  const char* ahb = (const char*)(AH + ((size_t)z * HWP + p0) * 256);
  const char* amb = (const char*)(AM + ((size_t)z * HWP + p0) * 256);
  const char* alb = (const char*)(AL + ((size_t)z * HWP + p0) * 256);
  const char* whb = (const char*)(WH + (size_t)o0 * 256);
  const char* wmb = (const char*)(WM + (size_t)o0 * 256);
  const char* wlb = (const char*)(WL + (size_t)o0 * 256);

  f32x4 acc[4][4];
#pragma unroll
  for (int i = 0; i < 4; ++i)
#pragma unroll
    for (int j = 0; j < 4; ++j) acc[i][j] = (f32x4){0.f, 0.f, 0.f, 0.f};

  for (int kc = 0; kc < 8; ++kc) {
    const int kof = kc * 64;
#pragma unroll
    for (int t = 0; t < 2; ++t) {
      int li = t * 256 + tid;
      int row = li >> 2, ch = li & 3;
      int chp = (ch - row - (row >> 2)) & 3;   // swizzled source granule
      size_t so = (size_t)row * 512 + kof + chp * 16;
      int base = (t * 256 + wave * 64) * 8;
      gl_lds16(ahb + so, &LAH[base]);
      gl_lds16(amb + so, &LAM[base]);
      gl_lds16(alb + so, &LAL[base]);
      gl_lds16(whb + so, &LWH[base]);
      gl_lds16(wmb + so, &LWM[base]);
      gl_lds16(wlb + so, &LWL[base]);
    }
    __syncthreads();
    short8 afH[4], afM[4], afL[4];
#pragma unroll
    for (int i = 0; i < 4; ++i) {
      int row = wm + i * 16 + lc;
      int o = row * 32 + ((lr + lc + (lc >> 2)) & 3) * 8;
      afH[i] = *(const short8*)&LAH[o];
      afM[i] = *(const short8*)&LAM[o];
      afL[i] = *(const short8*)&LAL[o];
    }
#pragma unroll
    for (int j = 0; j < 4; ++j) {
      int row = wn + j * 16 + lc;
      int o = row * 32 + ((lr + lc + (lc >> 2)) & 3) * 8;
      short8 bh = *(const short8*)&LWH[o];
      short8 bm = *(const short8*)&LWM[o];
      short8 bl = *(const short8*)&LWL[o];
#pragma unroll
      for (int i = 0; i < 4; ++i) {
        acc[i][j] = __builtin_amdgcn_mfma_f32_16x16x32_bf16(afM[i], bm, acc[i][j], 0, 0, 0);
        acc[i][j] = __builtin_amdgcn_mfma_f32_16x16x32_bf16(afL[i], bh, acc[i][j], 0, 0, 0);
        acc[i][j] = __builtin_amdgcn_mfma_f32_16x16x32_bf16(afH[i], bl, acc[i][j], 0, 0, 0);
        acc[i][j] = __builtin_amdgcn_mfma_f32_16x16x32_bf16(afM[i], bh, acc[i][j], 0, 0, 0);
        acc[i][j] = __builtin_amdgcn_mfma_f32_16x16x32_bf16(afH[i], bm, acc[i][j], 0, 0, 0);
        acc[i][j] = __builtin_amdgcn_mfma_f32_16x16x32_bf16(afH[i], bh, acc[i][j], 0, 0, 0);
      }
    }
    __syncthreads();
  }
  // Epilogue: channel-major, m = pixel, n = out-channel.
#pragma unroll
  for (int j = 0; j < 4; ++j) {
    int n = o0 + wn + j * 16 + lc;
    float bn_ = bias[n];
    size_t rowb = ((size_t)(b0 + z) * CCH + n) * HWP + p0;
#pragma unroll
    for (int i = 0; i < 4; ++i) {
      int m = wm + i * 16 + lr * 4;
      if (MODE == 0) {
        float4 o;
        o.x = acc[i][j][0] + bn_; o.y = acc[i][j][1] + bn_;
        o.z = acc[i][j][2] + bn_; o.w = acc[i][j][3] + bn_;
        *(float4*)(outF + rowb + m) = o;
      } else {
        uchar4 o;
        o.x = (acc[i][j][0] + bn_ >= 2.0f) ? 1 : 0;
        o.y = (acc[i][j][1] + bn_ >= 2.0f) ? 1 : 0;
        o.z = (acc[i][j][2] + bn_ >= 2.0f) ? 1 : 0;
        o.w = (acc[i][j][3] + bn_ >= 2.0f) ? 1 : 0;
        *(uchar4*)(outB + rowb + m) = o;
      }
    }
  }
}

// ---------------------------------------------------------------------------
// Attention per (z,c), reordered: S = Q K^T (3-split x 3-split, 6 passes,
// frags direct from global for Q, K staged 3-split in NATURAL layout);
// attn = S V^T (S 3-split in LDS, V binary u8, 3 passes); s = (attn >= 8).
// 320 threads: wave = m-tile. LDS row stride 104 u16 (2-way b128 reads).
// ---------------------------------------------------------------------------
__global__ __launch_bounds__(320) void attn_k(
    const float* __restrict__ qf, const float* __restrict__ kf,
    const u8* __restrict__ vv, u8* __restrict__ s)
{
  __shared__ alignas(16) u16 L[24960];   // K 3-split [h'][w]; overlaid by S 3-split [h][h']
  __shared__ alignas(16) u8  VT[8320];   // V^T [u][h'] stride 104
  const int tid = threadIdx.x, wave = tid >> 6, lane = tid & 63;
  const int lc = lane & 15, lr = lane >> 4;
  const size_t off = (size_t)blockIdx.x * HWP;
  u16* KH = L; u16* KM = L + 8320; u16* KL = L + 16640;

  // zero k-pads (cols 80..95)
  for (int t = 0; t < 12; ++t) {
    int i = t * 320 + tid;
    if (i < 3840) {
      int pl = i / 1280, rem = i - pl * 1280;
      L[pl * 8320 + (rem >> 4) * 104 + 80 + (rem & 15)] = 0;
    }
  }
  for (int t = 0; t < 4; ++t) {
    int i = t * 320 + tid;
    if (i < 1280) VT[(i >> 4) * 104 + 80 + (i & 15)] = 0;
  }
  // stage K 3-split natural [h'][w] (conflict-free writes) + V^T u8
  for (int t = 0; t < 20; ++t) {
    int idx = t * 320 + tid;
    int h = idx / 80, w = idx - h * 80;
    u16 hh, mm, ll; split3(kf[off + idx], hh, mm, ll);
    KH[h * 104 + w] = hh; KM[h * 104 + w] = mm; KL[h * 104 + w] = ll;
    VT[w * 104 + h] = vv[off + idx];
  }
  __syncthreads();

  // Stage 1: S = Q K^T.  m-rows h = wave*16+lc, k = w (pad 96), n = h'.
  f32x4 accS[5];
#pragma unroll
  for (int n = 0; n < 5; ++n) accS[n] = (f32x4){0.f, 0.f, 0.f, 0.f};
  const int hrow = wave * 16 + lc;
  for (int kc = 0; kc < 3; ++kc) {
    short8 qh, qm, ql;
    int w0 = kc * 32 + lr * 8;
    if (w0 < 80) {
      const float* qp = qf + off + hrow * 80 + w0;
      float4 a = *(const float4*)qp;
      float4 b = *(const float4*)(qp + 4);
      float qv[8] = {a.x, a.y, a.z, a.w, b.x, b.y, b.z, b.w};
#pragma unroll
      for (int e = 0; e < 8; ++e) {
        u16 hh, mm, ll; split3(qv[e], hh, mm, ll);
        qh[e] = (short)hh; qm[e] = (short)mm; ql[e] = (short)ll;
      }
    } else {
      qh = (short8){0,0,0,0,0,0,0,0}; qm = qh; ql = qh;
    }
#pragma unroll
    for (int n = 0; n < 5; ++n) {
      int bo = (n * 16 + lc) * 104 + kc * 32 + lr * 8;
      short8 kh_ = *(const short8*)&KH[bo];
      short8 km_ = *(const short8*)&KM[bo];
      short8 kl_ = *(const short8*)&KL[bo];
      accS[n] = __builtin_amdgcn_mfma_f32_16x16x32_bf16(qh, kl_, accS[n], 0, 0, 0);
      accS[n] = __builtin_amdgcn_mfma_f32_16x16x32_bf16(ql, kh_, accS[n], 0, 0, 0);
      accS[n] = __builtin_amdgcn_mfma_f32_16x16x32_bf16(qm, km_, accS[n], 0, 0, 0);
      accS[n] = __builtin_amdgcn_mfma_f32_16x16x32_bf16(qm, kh_, accS[n], 0, 0, 0);
      accS[n] = __builtin_amdgcn_mfma_f32_16x16x32_bf16(qh, km_, accS[n], 0, 0, 0);
      accS[n] = __builtin_amdgcn_mfma_f32_16x16x32_bf16(qh, kh_, accS[n], 0, 0, 0);
    }
  }
  __syncthreads();   // all K reads done; L becomes S
  // zero S k-pads, write S 3-split [h][h']
  for (int t = 0; t < 12; ++t) {
    int i = t * 320 + tid;
    if (i < 3840) {
      int pl = i / 1280, rem = i - pl * 1280;
      L[pl * 8320 + (rem >> 4) * 104 + 80 + (rem & 15)] = 0;
    }
  }
#pragma unroll
  for (int n = 0; n < 5; ++n) {
#pragma unroll
    for (int r = 0; r < 4; ++r) {
      u16 hh, mm, ll; split3(accS[n][r], hh, mm, ll);
      int o = (wave * 16 + lr * 4 + r) * 104 + n * 16 + lc;
      KH[o] = hh; KM[o] = mm; KL[o] = ll;
    }
  }
  __syncthreads();
  // Stage 2: attn = S V ; spike at raw >= 8  (attn*0.125 >= 1)
  f32x4 accA[5];
#pragma unroll
  for (int n = 0; n < 5; ++n) accA[n] = (f32x4){0.f, 0.f, 0.f, 0.f};
  for (int kc = 0; kc < 3; ++kc) {
    int ao = (wave * 16 + lc) * 104 + kc * 32 + lr * 8;
    short8 sh_ = *(const short8*)&KH[ao];
    short8 sm_ = *(const short8*)&KM[ao];
    short8 sl_ = *(const short8*)&KL[ao];
#pragma unroll
    for (int n = 0; n < 5; ++n) {
      const u8* vp = &VT[(n * 16 + lc) * 104 + kc * 32 + lr * 8];
      u32 b0 = *(const u32*)vp;
      u32 b1 = *(const u32*)(vp + 4);
      u32 e0 = ((b0 & 255u) ? 0x3F80u : 0u) | (((b0 >> 8) & 255u) ? 0x3F800000u : 0u);
      u32 e1 = (((b0 >> 16) & 255u) ? 0x3F80u : 0u) | (((b0 >> 24) & 255u) ? 0x3F800000u : 0u);
      u32 e2 = ((b1 & 255u) ? 0x3F80u : 0u) | (((b1 >> 8) & 255u) ? 0x3F800000u : 0u);
      u32 e3 = (((b1 >> 16) & 255u) ? 0x3F80u : 0u) | (((b1 >> 24) & 255u) ? 0x3F800000u : 0u);
      u32 vbw[4] = {e0, e1, e2, e3};
      short8 vb = *(const short8*)vbw;
      accA[n] = __builtin_amdgcn_mfma_f32_16x16x32_bf16(sl_, vb, accA[n], 0, 0, 0);
      accA[n] = __builtin_amdgcn_mfma_f32_16x16x32_bf16(sm_, vb, accA[n], 0, 0, 0);
      accA[n] = __builtin_amdgcn_mfma_f32_16x16x32_bf16(sh_, vb, accA[n], 0, 0, 0);
    }
  }
#pragma unroll
  for (int n = 0; n < 5; ++n)
#pragma unroll
    for (int r = 0; r < 4; ++r)
      s[off + (size_t)(wave * 16 + lr * 4 + r) * 80 + n * 16 + lc] =
          (accA[n][r] >= 8.0f) ? 1 : 0;
}

// ---------------------------------------------------------------------------
extern "C" void kernel_launch(void* const* d_in, const int* in_sizes, int n_in,
                              void* d_out, int out_size, void* d_ws, size_t ws_size,
                              hipStream_t stream)
{
  const float* x   = (const float*)d_in[0];
  const float* w1  = (const float*)d_in[1];
  const float* dwk = (const float*)d_in[2];
  const float* w2  = (const float*)d_in[3];
  const float* bnp = (const float*)d_in[4];
  float* out = (float*)d_out;
  char* ws = (char*)d_ws;

  // Workspace layout (~292 MB total)
  u16* W1H = (u16*)(ws + 0);
  u16* W1M = (u16*)(ws + 524288);
  u16* W1L = (u16*)(ws + 1048576);
  u16* W2H = (u16*)(ws + 1572864);
  u16* W2M = (u16*)(ws + 2097152);
  u16* W2L = (u16*)(ws + 2621440);
  float* B0F = (float*)(ws + 3145728);
  float* B2F = (float*)(ws + 3149824);
  u8*    SPM = (u8*)(ws + 3153920);          // s pixel-major, full 16 batches
  u8*    XS  = (u8*)(ws + 29368320);         // xs, half-batch chunk
  float* T1  = (float*)(ws + 42475520);      // fp32 branch tmp, half chunk
  float* QF  = (float*)(ws + 94904320);      // q fp32 CM, half chunk
  float* KF  = (float*)(ws + 147333120);     // k fp32 CM, half chunk
  u8*    V   = (u8*)(ws + 199761920);        // v binary CM (s_cm in-place)
  u16*   D2H = (u16*)(ws + 212869120);       // dw split hi, pixel-major
  u16*   D2M = (u16*)(ws + 239083520);
  u16*   D2L = (u16*)(ws + 265297920);       // ends 291512320

  dim3 gb(256);
  fold_weights<<<dim3(1024), gb, 0, stream>>>(w1, w2, bnp,
      W1H, W1M, W1L, W2H, W2M, W2L, B0F, B2F);

  for (int c = 0; c < 2; ++c) {
    int b0 = c * 8;
    dim3 gh(100, 4, 8), gg(50, 2, 8), gd(1600, 8);
    head_spike<<<gh, gb, 0, stream>>>(x, XS, b0);
    // q branch
    gemm1<<<gg, gb, 0, stream>>>(XS, 0, W1H + 0 * 65536, W1M + 0 * 65536, W1L + 0 * 65536,
                                 B0F + 0, T1);
    dw3<<<gd, gb, 0, stream>>>(T1, dwk + 0 * 2304, D2H, D2M, D2L);
    gemm2s<0><<<gg, gb, 0, stream>>>(D2H, D2M, D2L,
                                     W2H + 0 * 65536, W2M + 0 * 65536, W2L + 0 * 65536,
                                     B2F + 0, 0, QF, nullptr);
    // k branch
    gemm1<<<gg, gb, 0, stream>>>(XS, 0, W1H + 1 * 65536, W1M + 1 * 65536, W1L + 1 * 65536,
                                 B0F + 256, T1);
    dw3<<<gd, gb, 0, stream>>>(T1, dwk + 1 * 2304, D2H, D2M, D2L);
    gemm2s<0><<<gg, gb, 0, stream>>>(D2H, D2M, D2L,
                                     W2H + 1 * 65536, W2M + 1 * 65536, W2L + 1 * 65536,
                                     B2F + 256, 0, KF, nullptr);
    // v branch (binary spike epilogue)
    gemm1<<<gg, gb, 0, stream>>>(XS, 0, W1H + 2 * 65536, W1M + 2 * 65536, W1L + 2 * 65536,
                                 B0F + 512, T1);
    dw3<<<gd, gb, 0, stream>>>(T1, dwk + 2 * 2304, D2H, D2M, D2L);
    gemm2s<1><<<gg, gb, 0, stream>>>(D2H, D2M, D2L,
                                     W2H + 2 * 65536, W2M + 2 * 65536, W2L + 2 * 65536,
                                     B2F + 512, 0, nullptr, V);
    // attention -> s channel-major (in-place over V), then to pixel-major SPM
    attn_k<<<dim3(2048), dim3(320), 0, stream>>>(QF, KF, V, V);
    transpose_s<<<gh, gb, 0, stream>>>(V, SPM, b0);
  }
  // proj branch -> fp32 d_out (channel-major), chunked to fit T1
  for (int c = 0; c < 2; ++c) {
    int b0 = c * 8;
    dim3 gg(50, 2, 8), gd(1600, 8);
    gemm1<<<gg, gb, 0, stream>>>(SPM, b0, W1H + 3 * 65536, W1M + 3 * 65536, W1L + 3 * 65536,
                                 B0F + 768, T1);
    dw3<<<gd, gb, 0, stream>>>(T1, dwk + 3 * 2304, D2H, D2M, D2L);
    gemm2s<0><<<gg, gb, 0, stream>>>(D2H, D2M, D2L,
                                     W2H + 3 * 65536, W2M + 3 * 65536, W2L + 3 * 65536,
                                     B2F + 768, b0, out, nullptr);
  }
}